// Round 16
// baseline (2328.832 us; speedup 1.0000x reference)
//
#include <hip/hip_runtime.h>
#include <hip/hip_bf16.h>

typedef unsigned int u32;
typedef unsigned short u16;
typedef _Float16 f16;
typedef float f32x4 __attribute__((ext_vector_type(4)));
typedef short bf16x8 __attribute__((ext_vector_type(8)));

#define CDIV(a,b) (((a)+(b)-1)/(b))

// ---------- helpers ----------
__device__ __forceinline__ float bf2f(u32 h){ return __uint_as_float(h<<16); }
__device__ __forceinline__ u16 f2bf(float f){
  u32 u=__float_as_uint(f);
  return (u16)((u + 0x7fffu + ((u>>16)&1u))>>16);   // RNE
}
__device__ __forceinline__ u32 fenc(float f){
  u32 u=__float_as_uint(f);
  return (u&0x80000000u)?~u:(u|0x80000000u);
}
__device__ __forceinline__ float fdec2(u32 e){
  u32 u=(e&0x80000000u)?(e&0x7fffffffu):~e;
  return __uint_as_float(u);
}
__device__ __forceinline__ void unpack8(const u16* p, float* xr){
  uint4 v=*(const uint4*)p;
  xr[0]=bf2f(v.x&0xffffu); xr[1]=bf2f(v.x>>16);
  xr[2]=bf2f(v.y&0xffffu); xr[3]=bf2f(v.y>>16);
  xr[4]=bf2f(v.z&0xffffu); xr[5]=bf2f(v.z>>16);
  xr[6]=bf2f(v.w&0xffffu); xr[7]=bf2f(v.w>>16);
}
__device__ __forceinline__ int iclamp(int i, int n){
  unsigned u=(unsigned)i; return (u>=(unsigned)n)?0:i;
}

struct EdgeTab {
  const int* dst[12];
  const int* src[12];
  int seo[13];
  int rpo[13];
  int nd[12];
  int ns[12];
};

struct GTab {
  int nn[6]; int xo[6];
  int rst[12]; int rdt[12];
  int aso[12], ado[12], rpo[12], seo[12];
  int tord[6]; int bofs[7];
  int abofs[7];
  int nrel[6], rel[6][6];
  int nrole[6]; int rwv[6][12]; int rofs[6][12];
  int dszb;
};

// ---------- misc ----------
__global__ void kdiag(float* out, int n, float v){
  int i=blockIdx.x*blockDim.x+threadIdx.x;
  if(i<n) out[i]=(i==0)?v:0.f;
}
__global__ void kzeroi(int* p, int n){
  int i=blockIdx.x*blockDim.x+threadIdx.x;
  if(i<n) p[i]=0;
}
__global__ void kbsum(const float* __restrict__ gb, float* __restrict__ bsum){
  int l=blockIdx.x/6, t=blockIdx.x%6, j=threadIdx.x;
  const int rd[12]={1,2,3,4,5,2,0,1,2,2,2,2};
  float a=0.f;
  #pragma unroll
  for(int r=0;r<12;++r) if(rd[r]==t) a += gb[(l*12+r)*64 + j];
  bsum[(l*6+t)*64 + j]=a;
}
__global__ void kwconv(const float* __restrict__ gw, u16* __restrict__ wt, int total){
  int o=blockIdx.x*blockDim.x+threadIdx.x;
  if(o>=total) return;
  int m=o>>12, rem=o&4095, j=rem>>6, k=rem&63;
  wt[o]=f2bf(gw[(m<<12)+(k<<6)+j]);
}
// wv vectors; also zeroes MG
__global__ void kwv(const float* __restrict__ gw, const float* __restrict__ gas,
                    const float* __restrict__ gad, float* __restrict__ wv,
                    u32* __restrict__ MG){
  int m=blockIdx.x;
  int lr=m>>1, role=m&1;
  int k=threadIdx.x;
  if(k==0){
    int l=lr/12, r=lr%12;
    MG[l*24+r*2+role]=0u;
  }
  const float* a=(role?gad:gas)+(size_t)lr*64;
  const float* W=gw+(size_t)lr*4096;
  float acc=0.f;
  for(int j=0;j<64;++j) acc += W[k*64+j]*a[j];
  wv[(size_t)m*64+k]=acc;
}

// ---------- CSR build (XCD-aligned chunks: chunk = blockIdx.x % nch) ----------
__global__ void khistX(EdgeTab et, int* __restrict__ RP, int Etot, int nch, int CS){
  int chunk=blockIdx.x%nch;
  int i=(blockIdx.x/nch)*blockDim.x+threadIdx.x;
  if(i>=Etot) return;
  int r=0;
  #pragma unroll
  for(int k=1;k<12;++k) r += (i>=et.seo[k]) ? 1 : 0;
  int e=i-et.seo[r];
  int rpidx=et.rpo[r]+iclamp(et.dst[r][e], et.nd[r]);
  int c0=chunk*CS;
  if(rpidx>=c0 && rpidx<c0+CS) atomicAdd(RP+rpidx,1);
}
__global__ void kscan1(const int* __restrict__ hist, int* __restrict__ rp, int* __restrict__ bsum, int N){
  __shared__ int lds[256];
  __shared__ int pref[256];
  int b=blockIdx.x, t=threadIdx.x;
  int base=b*4096+t*16;
  int v[16]; int s=0;
  #pragma unroll
  for(int k=0;k<16;++k){ int idx=base+k; v[k]=(idx<N)?hist[idx]:0; s+=v[k]; }
  lds[t]=s; __syncthreads();
  if(t==0){ int run=0; for(int i=0;i<256;++i){ pref[i]=run; run+=lds[i]; } bsum[b]=run; }
  __syncthreads();
  int run=pref[t];
  #pragma unroll
  for(int k=0;k<16;++k){ int idx=base+k; if(idx<N) rp[idx]=run; run+=v[k]; }
}
__global__ void kscan2b(int* bsum, int nb){
  __shared__ int lds[256], pref[256], tot;
  int t=threadIdx.x;
  int v[4]; int s=0;
  #pragma unroll
  for(int k=0;k<4;++k){ int idx=t*4+k; v[k]=(idx<nb)?bsum[idx]:0; s+=v[k]; }
  lds[t]=s; __syncthreads();
  if(t==0){ int run=0; for(int i=0;i<256;++i){ pref[i]=run; run+=lds[i]; } tot=run; }
  __syncthreads();
  int run=pref[t];
  #pragma unroll
  for(int k=0;k<4;++k){ int idx=t*4+k; if(idx<nb){ int x=v[k]; bsum[idx]=run; run+=x; } }
  if(t==0) bsum[nb]=tot;
}
__global__ void kscan3(int* __restrict__ rp, const int* __restrict__ bsum, int N){
  int i=blockIdx.x*blockDim.x+threadIdx.x;
  if(i<N) rp[i]+=bsum[i>>12];
}
__global__ void kscatterX(EdgeTab et, int* __restrict__ RP, int* __restrict__ SRCS,
                          int Etot, int nch, int CS){
  int chunk=blockIdx.x%nch;
  int i=(blockIdx.x/nch)*blockDim.x+threadIdx.x;
  if(i>=Etot) return;
  int r=0;
  #pragma unroll
  for(int k=1;k<12;++k) r += (i>=et.seo[k]) ? 1 : 0;
  int e=i-et.seo[r];
  int rpidx=et.rpo[r]+iclamp(et.dst[r][e], et.nd[r]);
  int c0=chunk*CS;
  if(rpidx>=c0 && rpidx<c0+CS){
    int pos=atomicAdd(RP+rpidx,1);
    SRCS[pos]=iclamp(et.src[r][e], et.ns[r]);
  }
}

// ---------- embeddings (+ fused layer-0 alphas) ----------
template<int D>
__global__ void kemb(const float* __restrict__ xin, const float* __restrict__ W,
                     const float* __restrict__ b, u16* __restrict__ xout, int N,
                     const float* __restrict__ WV0, f16* __restrict__ AA, GTab tab, int t){
  int n=blockIdx.x*blockDim.x+threadIdx.x;
  if(n>=N) return;
  float xr[D];
  #pragma unroll
  for(int k=0;k<D;++k) xr[k]=xin[(long)n*D+k];
  float o[64];
  u16* orow=xout+(long)n*64;
  #pragma unroll
  for(int j0=0;j0<64;j0+=8){
    #pragma unroll
    for(int jj=0;jj<8;++jj){
      float a=b[j0+jj];
      #pragma unroll
      for(int k=0;k<D;++k) a += xr[k]*W[k*64+j0+jj];
      o[j0+jj]=a;
    }
    uint4 pk;
    pk.x=(u32)f2bf(o[j0+0])|((u32)f2bf(o[j0+1])<<16);
    pk.y=(u32)f2bf(o[j0+2])|((u32)f2bf(o[j0+3])<<16);
    pk.z=(u32)f2bf(o[j0+4])|((u32)f2bf(o[j0+5])<<16);
    pk.w=(u32)f2bf(o[j0+6])|((u32)f2bf(o[j0+7])<<16);
    *(uint4*)(orow+j0)=pk;
  }
  int nr=tab.nrole[t];
  for(int ro=0;ro<nr;++ro){
    const float* wv=WV0+(size_t)tab.rwv[t][ro]*64;
    float acc=0.f;
    #pragma unroll
    for(int k=0;k<64;++k) acc += o[k]*wv[k];
    AA[tab.rofs[t][ro]+n]=(f16)acc;
  }
}

// ---------- merged alpha (layers 1,2) ----------
__global__ void kalphaM(const u16* __restrict__ X, const float* __restrict__ WVl,
                        f16* __restrict__ AA, GTab tab){
  __shared__ float wv[12*64];
  int b=blockIdx.x, tid=threadIdx.x;
  int ti=0;
  #pragma unroll
  for(int k=1;k<6;++k) ti += (b>=tab.abofs[k]) ? 1 : 0;
  int t=tab.tord[ti];
  int nr=tab.nrole[t];
  for(int i=tid;i<nr*64;i+=256){
    int ro=i>>6, j=i&63;
    wv[i]=WVl[tab.rwv[t][ro]*64+j];
  }
  __syncthreads();
  int nid=(b-tab.abofs[ti])*256+tid;
  if(nid>=tab.nn[t]) return;
  const u16* row=X+((long)tab.xo[t]+nid)*64;
  float xr[64];
  #pragma unroll
  for(int j=0;j<64;j+=8) unpack8(row+j,xr+j);
  for(int ro=0;ro<nr;++ro){
    float acc=0.f;
    #pragma unroll
    for(int k=0;k<64;++k) acc += xr[k]*wv[ro*64+k];
    AA[tab.rofs[t][ro]+nid]=(f16)acc;
  }
}

// ---------- per-role max over AA segments ----------
__global__ void kmg(const f16* __restrict__ AA, u32* __restrict__ MGl, GTab tab){
  const int NB=8;
  int b=blockIdx.x;
  int ro=b/NB, part=b%NB;
  int r=ro>>1, role=ro&1;
  int base,len;
  if(role==0){ base=tab.aso[r];           len=tab.nn[tab.rst[r]]; }
  else       { base=tab.dszb+tab.ado[r];  len=tab.nn[tab.rdt[r]]; }
  int i0=(int)((long)len*part/NB), i1=(int)((long)len*(part+1)/NB);
  float m=-3.4e38f;
  for(int i=i0+threadIdx.x;i<i1;i+=256) m=fmaxf(m,(float)AA[base+i]);
  #pragma unroll
  for(int off=32;off;off>>=1) m=fmaxf(m,__shfl_xor(m,off));
  __shared__ float red[4];
  if((threadIdx.x&63)==0) red[threadIdx.x>>6]=m;
  __syncthreads();
  if(threadIdx.x==0){
    float mm=fmaxf(fmaxf(red[0],red[1]),fmaxf(red[2],red[3]));
    atomicMax(MGl+ro,fenc(mm));
  }
}

// ---------- gather + WT-stage device helpers ----------
__device__ __forceinline__ void stage_wt(const u16* __restrict__ WTl, int r, int tid, char* wbuf){
  const uint4* s4=(const uint4*)(WTl+(size_t)r*4096);
  uint4 v0=s4[tid*2], v1=s4[tid*2+1];
  int b0=tid*32, j=b0>>7;
  *(uint4*)(wbuf+((b0   )^((j&7)<<4)))=v0;
  *(uint4*)(wbuf+((b0+16)^((j&7)<<4)))=v1;
}

__device__ __forceinline__ void gather_z(int r, int d, int Nt, int nid, int q,
                                         const f16* __restrict__ AA,
                                         const int* __restrict__ RP,
                                         const int* __restrict__ SRCS,
                                         const u16* __restrict__ Xc,
                                         const u32* __restrict__ MGl,
                                         const GTab& tab, char* zbuf){
  float msum=fdec2(MGl[r*2])+fdec2(MGl[r*2+1]);
  float m = msum>=0.f? msum : 0.2f*msum;
  float z[16];
  #pragma unroll
  for(int k=0;k<16;++k) z[k]=0.f;
  float sden=0.f;
  if(d<Nt){
    int b1=RP[tab.rpo[r]+d];
    int b0e= d? RP[tab.rpo[r]+d-1] : tab.seo[r];
    float adv=(float)AA[tab.dszb+tab.ado[r]+d];
    const u16* xbase=Xc+(long)tab.xo[tab.rst[r]]*64;
    const f16* asp=AA+tab.aso[r];
    int e=b0e;
    for(; e+1<b1; e+=2){
      int sr0=SRCS[e], sr1=SRCS[e+1];
      float ev0=(float)asp[sr0]+adv; ev0 = ev0>=0.f?ev0:0.2f*ev0;
      float ev1=(float)asp[sr1]+adv; ev1 = ev1>=0.f?ev1:0.2f*ev1;
      float p0=__expf(ev0-m), p1=__expf(ev1-m);
      const u16* rw0=xbase+(long)sr0*64+q*16;
      const u16* rw1=xbase+(long)sr1*64+q*16;
      uint4 a0=*(const uint4*)rw0;
      uint4 a1=*(const uint4*)(rw0+8);
      uint4 c0=*(const uint4*)rw1;
      uint4 c1=*(const uint4*)(rw1+8);
      sden+=p0+p1;
      float xr[8];
      unpack8((const u16*)&a0,xr);
      #pragma unroll
      for(int k=0;k<8;++k) z[k]+=p0*xr[k];
      unpack8((const u16*)&a1,xr);
      #pragma unroll
      for(int k=0;k<8;++k) z[8+k]+=p0*xr[k];
      unpack8((const u16*)&c0,xr);
      #pragma unroll
      for(int k=0;k<8;++k) z[k]+=p1*xr[k];
      unpack8((const u16*)&c1,xr);
      #pragma unroll
      for(int k=0;k<8;++k) z[8+k]+=p1*xr[k];
    }
    if(e<b1){
      int sr0=SRCS[e];
      float ev0=(float)asp[sr0]+adv; ev0 = ev0>=0.f?ev0:0.2f*ev0;
      float p0=__expf(ev0-m);
      const u16* rw0=xbase+(long)sr0*64+q*16;
      uint4 a0=*(const uint4*)rw0;
      uint4 a1=*(const uint4*)(rw0+8);
      sden+=p0;
      float xr[8];
      unpack8((const u16*)&a0,xr);
      #pragma unroll
      for(int k=0;k<8;++k) z[k]+=p0*xr[k];
      unpack8((const u16*)&a1,xr);
      #pragma unroll
      for(int k=0;k<8;++k) z[8+k]+=p0*xr[k];
    }
  }
  float inv=1.f/(sden+1e-16f);
  uint4 p0,p1;
  p0.x=(u32)f2bf(z[0]*inv) |((u32)f2bf(z[1]*inv)<<16);
  p0.y=(u32)f2bf(z[2]*inv) |((u32)f2bf(z[3]*inv)<<16);
  p0.z=(u32)f2bf(z[4]*inv) |((u32)f2bf(z[5]*inv)<<16);
  p0.w=(u32)f2bf(z[6]*inv) |((u32)f2bf(z[7]*inv)<<16);
  p1.x=(u32)f2bf(z[8]*inv) |((u32)f2bf(z[9]*inv)<<16);
  p1.y=(u32)f2bf(z[10]*inv)|((u32)f2bf(z[11]*inv)<<16);
  p1.z=(u32)f2bf(z[12]*inv)|((u32)f2bf(z[13]*inv)<<16);
  p1.w=(u32)f2bf(z[14]*inv)|((u32)f2bf(z[15]*inv)<<16);
  int zb=nid*128+q*32;
  *(uint4*)(zbuf+((zb   )^((nid&7)<<4)))=p0;
  *(uint4*)(zbuf+((zb+16)^((nid&7)<<4)))=p1;
}

// ---------- merged fused GAT (pipelined: gather_{r+1} || MFMA_r) ----------
__global__ void kfusedM2(const u16* __restrict__ Xc, u16* __restrict__ Xn,
                         const u16* __restrict__ WTl, const f16* __restrict__ AA,
                         const int* __restrict__ RP, const int* __restrict__ SRCS,
                         const float* __restrict__ BSl, const u32* __restrict__ MGl,
                         GTab tab){
  __shared__ char Lraw[32768];         // [ZB0|ZB1|WB0|WB1] 8KB each; C reuses [0,16K)
  char* L=(char*)Lraw;
  int tid=threadIdx.x;
  int b=blockIdx.x;
  int ti=0;
  #pragma unroll
  for(int k=1;k<6;++k) ti += (b>=tab.bofs[k]) ? 1 : 0;
  int t=tab.tord[ti];
  int d0=(b-tab.bofs[ti])*64;
  int Nt=tab.nn[t];
  int nid=tid>>2, q=tid&3;
  int d=d0+nid;

  f32x4 acc[4];
  #pragma unroll
  for(int ct=0;ct<4;++ct){ acc[ct][0]=0.f; acc[ct][1]=0.f; acc[ct][2]=0.f; acc[ct][3]=0.f; }

  int nrel=tab.nrel[t];
  gather_z(tab.rel[t][0],d,Nt,nid,q,AA,RP,SRCS,Xc,MGl,tab,L);
  stage_wt(WTl,tab.rel[t][0],tid,L+16384);
  __syncthreads();

  for(int ri=0;ri<nrel;++ri){
    int zcur = (ri&1)? 8192 : 0;
    int wcur = 16384 + zcur;
    if(ri+1<nrel){
      int znxt = (ri&1)? 0 : 8192;
      gather_z(tab.rel[t][ri+1],d,Nt,nid,q,AA,RP,SRCS,Xc,MGl,tab,L+znxt);
      stage_wt(WTl,tab.rel[t][ri+1],tid,L+16384+znxt);
    }
    {
      int w=tid>>6, l=tid&63;
      int nt=w*16;
      int arow=nt+(l&15);
      int kb=(l>>4)*8;
      #pragma unroll
      for(int ks=0;ks<64;ks+=32){
        int ab=arow*128+(ks+kb)*2;
        uint4 av=*(uint4*)(L+zcur+(ab^((arow&7)<<4)));
        bf16x8 af=*(bf16x8*)&av;
        #pragma unroll
        for(int ct=0;ct<4;++ct){
          int jrow=ct*16+(l&15);
          int bb=jrow*128+(ks+kb)*2;
          uint4 bv=*(uint4*)(L+wcur+(bb^((jrow&7)<<4)));
          bf16x8 bfr=*(bf16x8*)&bv;
          acc[ct]=__builtin_amdgcn_mfma_f32_16x16x32_bf16(af,bfr,acc[ct],0,0,0);
        }
      }
    }
    __syncthreads();
  }

  // C -> LDS (reuse [0,16K))
  {
    int w=tid>>6, l=tid&63;
    int nt=w*16;
    #pragma unroll
    for(int ct=0;ct<4;++ct){
      #pragma unroll
      for(int r4=0;r4<4;++r4){
        int crow=nt+(l>>4)*4+r4;
        int ccol=ct*16+(l&15);
        int cb=crow*256+ccol*4;
        *(float*)(L+(cb^((crow&7)<<4)))=acc[ct][r4];
      }
    }
  }
  __syncthreads();
  {
    int nn=tid>>2, cq=tid&3;
    if(d0+nn<Nt){
      float cv[16];
      #pragma unroll
      for(int p=0;p<4;++p){
        int cb=nn*256+cq*64+p*16;
        uint4 v=*(uint4*)(L+(cb^((nn&7)<<4)));
        const float* f=(const float*)&v;
        cv[p*4+0]=f[0]; cv[p*4+1]=f[1]; cv[p*4+2]=f[2]; cv[p*4+3]=f[3];
      }
      const float* bs=BSl+t*64+cq*16;
      u32 wd[8];
      #pragma unroll
      for(int i=0;i<8;++i){
        float lo=fmaxf(cv[2*i]  +bs[2*i],  0.f);
        float hi=fmaxf(cv[2*i+1]+bs[2*i+1],0.f);
        wd[i]=(u32)f2bf(lo)|((u32)f2bf(hi)<<16);
      }
      u16* orow=Xn+((long)tab.xo[t]+d0+nn)*64+cq*16;
      uint4 s0; s0.x=wd[0]; s0.y=wd[1]; s0.z=wd[2]; s0.w=wd[3];
      uint4 s1; s1.x=wd[4]; s1.y=wd[5]; s1.z=wd[6]; s1.w=wd[7];
      *(uint4*)orow=s0;
      *(uint4*)(orow+8)=s1;
    }
  }
}

// classifier
__global__ void kcls(const u16* __restrict__ tx, const float* __restrict__ W1,
                     const float* __restrict__ b1, const float* __restrict__ W2,
                     const float* __restrict__ b2, float* __restrict__ out, int N){
  int n=blockIdx.x*blockDim.x+threadIdx.x;
  if(n>=N) return;
  const u16* row=tx+(long)n*64;
  float xr[64];
  #pragma unroll
  for(int j=0;j<64;j+=8) unpack8(row+j,xr+j);
  float acc2=0.f;
  for(int j=0;j<64;++j){
    float a=b1[j];
    #pragma unroll
    for(int k=0;k<64;++k) a += xr[k]*W1[k*64+j];
    a=fmaxf(a,0.f);
    acc2 += a*W2[j];
  }
  float zv=acc2+b2[0];
  out[n]=1.f/(1.f+__expf(-zv));
}

// ---------- pooling ----------
__global__ void kgrp(const int* __restrict__ batch, int* __restrict__ grp, int N){
  int g=blockIdx.x*blockDim.x+threadIdx.x;
  if(g>1024) return;
  if(g==1024){ grp[1024]=N; return; }
  int lo=0, hi=N;
  while(lo<hi){ int mid=(lo+hi)>>1; if(batch[mid]<g) lo=mid+1; else hi=mid; }
  grp[g]=lo;
}
__global__ void kpoolf(const u16* __restrict__ tx, const int* __restrict__ grp,
                       const float* __restrict__ pW, const float* __restrict__ pb,
                       float* __restrict__ out){
  __shared__ float S[256], M[256], V[128];
  int g=blockIdx.x, t=threadIdx.x, w=t>>6, j=t&63;
  int n0=grp[g], n1=grp[g+1];
  float s=0.f, m=-3.4e38f;
  for(int n=n0+w; n<n1; n+=4){
    float v=bf2f(tx[(long)n*64+j]);
    s+=v; m=fmaxf(m,v);
  }
  S[t]=s; M[t]=m; __syncthreads();
  if(t<64){
    float ss=S[t]+S[t+64]+S[t+128]+S[t+192];
    float mm=fmaxf(fmaxf(M[t],M[t+64]),fmaxf(M[t+128],M[t+192]));
    int cnt=n1-n0;
    V[t]=ss/fmaxf((float)cnt,1.f);
    V[64+t]=(cnt>0)?mm:0.f;
  }
  __syncthreads();
  if(t<64){
    float acc=pb[t];
    for(int k=0;k<128;++k) acc+=V[k]*pW[k*64+t];
    out[(long)g*64+t]=acc;
  }
}

// ---------- host ----------
extern "C" void kernel_launch(void* const* d_in, const int* in_sizes, int n_in,
                              void* d_out, int out_size, void* d_ws, size_t ws_size,
                              hipStream_t stream){
  const int   NN[6]={100000,150000,500000,20000,5000,50000};
  const long  XO[6]={0,100000,250000,750000,770000,775000};
  const int   RS[12]={0,1,2,2,2,2,1,2,3,4,5,2};
  const int   RD[12]={1,2,3,4,5,2,0,1,2,2,2,2};
  const int   EC[12]={150000,500000,500000,500000,500000,500000,150000,500000,500000,500000,500000,500000};

  const float* xin[6];  for(int t=0;t<6;++t) xin[t]=(const float*)d_in[t];
  const float* embW[6]; const float* embB[6];
  for(int t=0;t<6;++t){ embW[t]=(const float*)d_in[6+2*t]; embB[t]=(const float*)d_in[7+2*t]; }
  const float* gatW =(const float*)d_in[18];
  const float* gatAs=(const float*)d_in[19];
  const float* gatAd=(const float*)d_in[20];
  const float* gatB =(const float*)d_in[21];
  const float* poolW=(const float*)d_in[22];
  const float* poolB=(const float*)d_in[23];
  const float* W1=(const float*)d_in[24];
  const float* b1=(const float*)d_in[25];
  const float* W2=(const float*)d_in[26];
  const float* b2=(const float*)d_in[27];
  const int* esrc[12]; const int* edst[12];
  for(int r=0;r<12;++r){ esrc[r]=(const int*)d_in[28+2*r]; edst[r]=(const int*)d_in[29+2*r]; }
  const int* batch=(const int*)d_in[52];
  float* out=(float*)d_out;
  (void)in_sizes; (void)n_in;

  EdgeTab et;
  GTab tab;
  int rpo=0, seo=0, asz=0, dsz=0;
  for(int r=0;r<12;++r){
    et.dst[r]=edst[r]; et.src[r]=esrc[r];
    et.seo[r]=seo; et.rpo[r]=rpo;
    et.nd[r]=NN[RD[r]]; et.ns[r]=NN[RS[r]];
    tab.rst[r]=RS[r]; tab.rdt[r]=RD[r];
    tab.seo[r]=seo; tab.rpo[r]=rpo;
    tab.aso[r]=asz; tab.ado[r]=dsz;
    seo+=EC[r]; rpo+=NN[RD[r]]+1;
    asz+=NN[RS[r]]; dsz+=NN[RD[r]];
  }
  et.seo[12]=seo; et.rpo[12]=rpo;
  const int Etot=seo;
  const int RPtot=rpo;
  tab.dszb=asz;
  for(int t=0;t<6;++t){ tab.nn[t]=NN[t]; tab.xo[t]=(int)XO[t]; }
  const int TORD[6]={4,3,5,2,1,0};
  int bo=0, abo=0;
  for(int i=0;i<6;++i){
    int t=TORD[i];
    tab.tord[i]=t;
    tab.bofs[i]=bo;   bo+=CDIV(NN[t],64);
    tab.abofs[i]=abo; abo+=CDIV(NN[t],256);
  }
  tab.bofs[6]=bo; tab.abofs[6]=abo;
  for(int t=0;t<6;++t){ tab.nrel[t]=0; tab.nrole[t]=0; }
  for(int r=0;r<12;++r){
    int dt=RD[r];
    tab.rel[dt][tab.nrel[dt]++]=r;
    int st=RS[r];
    tab.rwv[st][tab.nrole[st]]=r*2+0;   tab.rofs[st][tab.nrole[st]++]=tab.aso[r];
    tab.rwv[dt][tab.nrole[dt]]=r*2+1;   tab.rofs[dt][tab.nrole[dt]++]=asz+tab.ado[r];
  }

  // ---- workspace ----
  char* w=(char*)d_ws;
  size_t off=0;
  auto take=[&](size_t bytes)->void*{
    void* p=w+off; off+=(bytes+(size_t)255)&~(size_t)255; return p;
  };
  u16*   X1   =(u16*)  take(105600000);
  u16*   X2   =(u16*)  take(105600000);
  int*   RP   =(int*)  take((size_t)RPtot*4);
  int*   SRCS =(int*)  take((size_t)Etot*4);
  int*   BS   =(int*)  take(4096);
  f16*   AA   =(f16*)  take((size_t)(asz+dsz)*2);
  float* WV   =(float*)take(72*64*4);
  float* BSUM =(float*)take(4608);
  int*   GRP  =(int*)  take(4104);
  u16*   WT   =(u16*)  take(294912);
  u32*   MG   =(u32*)  take(288);
  size_t need=off;

  const int B=256;

  if(ws_size<need){
    kdiag<<<CDIV(out_size,B),B,0,stream>>>(out,out_size,(float)(ws_size>>20));
    return;
  }

  // weight prep (kwv also zeroes MG)
  kwconv<<<CDIV(147456,B),B,0,stream>>>(gatW,WT,147456);
  kwv<<<72,64,0,stream>>>(gatW,gatAs,gatAd,WV,MG);
  kbsum<<<18,64,0,stream>>>(gatB,BSUM);

  // CSR build: XCD-aligned chunked hist + scan + XCD-aligned chunked scatter
  const int NCH=8;
  int CS=CDIV(RPtot,NCH);
  int nbe=CDIV(Etot,B);
  int nbs=CDIV(RPtot,4096);
  kzeroi<<<CDIV(RPtot,B),B,0,stream>>>(RP,RPtot);
  khistX<<<NCH*nbe,B,0,stream>>>(et,RP,Etot,NCH,CS);
  kscan1<<<nbs,256,0,stream>>>(RP,RP,BS,RPtot);
  kscan2b<<<1,256,0,stream>>>(BS,nbs);
  kscan3<<<CDIV(RPtot,B),B,0,stream>>>(RP,BS,RPtot);
  kscatterX<<<NCH*nbe,B,0,stream>>>(et,RP,SRCS,Etot,NCH,CS);

  // embeddings (+ layer-0 alphas) -> X1
  kemb< 8><<<CDIV(NN[0],B),B,0,stream>>>(xin[0],embW[0],embB[0],X1+XO[0]*64,NN[0],WV,AA,tab,0);
  kemb< 6><<<CDIV(NN[1],B),B,0,stream>>>(xin[1],embW[1],embB[1],X1+XO[1]*64,NN[1],WV,AA,tab,1);
  kemb<12><<<CDIV(NN[2],B),B,0,stream>>>(xin[2],embW[2],embB[2],X1+XO[2]*64,NN[2],WV,AA,tab,2);
  kemb< 6><<<CDIV(NN[3],B),B,0,stream>>>(xin[3],embW[3],embB[3],X1+XO[3]*64,NN[3],WV,AA,tab,3);
  kemb< 5><<<CDIV(NN[4],B),B,0,stream>>>(xin[4],embW[4],embB[4],X1+XO[4]*64,NN[4],WV,AA,tab,4);
  kemb< 5><<<CDIV(NN[5],B),B,0,stream>>>(xin[5],embW[5],embB[5],X1+XO[5]*64,NN[5],WV,AA,tab,5);

  u16* Xc=X1; u16* Xn=X2;
  for(int l=0;l<3;++l){
    if(l>0) kalphaM<<<abo,256,0,stream>>>(Xc,WV+(size_t)l*1536,AA,tab);
    kmg<<<24*8,256,0,stream>>>(AA,MG+(size_t)l*24,tab);
    kfusedM2<<<bo,256,0,stream>>>(Xc,Xn,WT+(size_t)l*49152,AA,RP,SRCS,
                                  BSUM+(size_t)l*384,MG+(size_t)l*24,tab);
    u16* tmp=Xc; Xc=Xn; Xn=tmp;
  }

  kcls<<<CDIV(NN[2],B),B,0,stream>>>(Xc+XO[2]*64,W1,b1,W2,b2,out,NN[2]);

  kgrp<<<CDIV(1025,B),B,0,stream>>>(batch,GRP,NN[2]);
  kpoolf<<<1024,256,0,stream>>>(Xc+XO[2]*64,GRP,poolW,poolB,out+500000);
}

// Round 18
// 2313.356 us; speedup vs baseline: 1.0067x; 1.0067x over previous
//
#include <hip/hip_runtime.h>
#include <hip/hip_bf16.h>

typedef unsigned int u32;
typedef unsigned short u16;
typedef _Float16 f16;
typedef float f32x4 __attribute__((ext_vector_type(4)));
typedef short bf16x8 __attribute__((ext_vector_type(8)));
typedef unsigned int u32x4 __attribute__((ext_vector_type(4)));

#define CDIV(a,b) (((a)+(b)-1)/(b))

// ---------- helpers ----------
__device__ __forceinline__ float bf2f(u32 h){ return __uint_as_float(h<<16); }
__device__ __forceinline__ u16 f2bf(float f){
  u32 u=__float_as_uint(f);
  return (u16)((u + 0x7fffu + ((u>>16)&1u))>>16);   // RNE
}
__device__ __forceinline__ u32 fenc(float f){
  u32 u=__float_as_uint(f);
  return (u&0x80000000u)?~u:(u|0x80000000u);
}
__device__ __forceinline__ float fdec2(u32 e){
  u32 u=(e&0x80000000u)?(e&0x7fffffffu):~e;
  return __uint_as_float(u);
}
__device__ __forceinline__ void unpack8(const u16* p, float* xr){
  uint4 v=*(const uint4*)p;
  xr[0]=bf2f(v.x&0xffffu); xr[1]=bf2f(v.x>>16);
  xr[2]=bf2f(v.y&0xffffu); xr[3]=bf2f(v.y>>16);
  xr[4]=bf2f(v.z&0xffffu); xr[5]=bf2f(v.z>>16);
  xr[6]=bf2f(v.w&0xffffu); xr[7]=bf2f(v.w>>16);
}
__device__ __forceinline__ int iclamp(int i, int n){
  unsigned u=(unsigned)i; return (u>=(unsigned)n)?0:i;
}

struct EdgeTab {
  const int* dst[12];
  const int* src[12];
  int seo[13];
  int rpo[13];
  int nd[12];
  int ns[12];
};

struct GTab {
  int nn[6]; int xo[6];
  int rst[12]; int rdt[12];
  int aso[12], ado[12], rpo[12], seo[12];
  int tord[6]; int bofs[7];
  int abofs[7];
  int nrel[6], rel[6][6];
  int nrole[6]; int rwv[6][12]; int rofs[6][12];
  int dszb;
};

// ---------- misc ----------
__global__ void kdiag(float* out, int n, float v){
  int i=blockIdx.x*blockDim.x+threadIdx.x;
  if(i<n) out[i]=(i==0)?v:0.f;
}
__global__ void kzeroi(int* p, int n){
  int i=blockIdx.x*blockDim.x+threadIdx.x;
  if(i<n) p[i]=0;
}
__global__ void kbsum(const float* __restrict__ gb, float* __restrict__ bsum){
  int l=blockIdx.x/6, t=blockIdx.x%6, j=threadIdx.x;
  const int rd[12]={1,2,3,4,5,2,0,1,2,2,2,2};
  float a=0.f;
  #pragma unroll
  for(int r=0;r<12;++r) if(rd[r]==t) a += gb[(l*12+r)*64 + j];
  bsum[(l*6+t)*64 + j]=a;
}
__global__ void kwconv(const float* __restrict__ gw, u16* __restrict__ wt, int total){
  int o=blockIdx.x*blockDim.x+threadIdx.x;
  if(o>=total) return;
  int m=o>>12, rem=o&4095, j=rem>>6, k=rem&63;
  wt[o]=f2bf(gw[(m<<12)+(k<<6)+j]);
}
// wv vectors; also zeroes MG
__global__ void kwv(const float* __restrict__ gw, const float* __restrict__ gas,
                    const float* __restrict__ gad, float* __restrict__ wv,
                    u32* __restrict__ MG){
  int m=blockIdx.x;
  int lr=m>>1, role=m&1;
  int k=threadIdx.x;
  if(k==0){
    int l=lr/12, r=lr%12;
    MG[l*24+r*2+role]=0u;
  }
  const float* a=(role?gad:gas)+(size_t)lr*64;
  const float* W=gw+(size_t)lr*4096;
  float acc=0.f;
  for(int j=0;j<64;++j) acc += W[k*64+j]*a[j];
  wv[(size_t)m*64+k]=acc;
}

// ---------- CSR build (single-pass) ----------
__global__ void khistAll(EdgeTab et, int* __restrict__ RP, int Etot){
  int i=blockIdx.x*blockDim.x+threadIdx.x;
  if(i>=Etot) return;
  int r=0;
  #pragma unroll
  for(int k=1;k<12;++k) r += (i>=et.seo[k]) ? 1 : 0;
  int e=i-et.seo[r];
  int d=iclamp(et.dst[r][e], et.nd[r]);
  atomicAdd(RP+et.rpo[r]+d,1);
}
__global__ void kscan1(const int* __restrict__ hist, int* __restrict__ rp, int* __restrict__ bsum, int N){
  __shared__ int lds[256];
  __shared__ int pref[256];
  int b=blockIdx.x, t=threadIdx.x;
  int base=b*4096+t*16;
  int v[16]; int s=0;
  #pragma unroll
  for(int k=0;k<16;++k){ int idx=base+k; v[k]=(idx<N)?hist[idx]:0; s+=v[k]; }
  lds[t]=s; __syncthreads();
  if(t==0){ int run=0; for(int i=0;i<256;++i){ pref[i]=run; run+=lds[i]; } bsum[b]=run; }
  __syncthreads();
  int run=pref[t];
  #pragma unroll
  for(int k=0;k<16;++k){ int idx=base+k; if(idx<N) rp[idx]=run; run+=v[k]; }
}
__global__ void kscan2b(int* bsum, int nb){
  __shared__ int lds[256], pref[256], tot;
  int t=threadIdx.x;
  int v[4]; int s=0;
  #pragma unroll
  for(int k=0;k<4;++k){ int idx=t*4+k; v[k]=(idx<nb)?bsum[idx]:0; s+=v[k]; }
  lds[t]=s; __syncthreads();
  if(t==0){ int run=0; for(int i=0;i<256;++i){ pref[i]=run; run+=lds[i]; } tot=run; }
  __syncthreads();
  int run=pref[t];
  #pragma unroll
  for(int k=0;k<4;++k){ int idx=t*4+k; if(idx<nb){ int x=v[k]; bsum[idx]=run; run+=x; } }
  if(t==0) bsum[nb]=tot;
}
__global__ void kscan3(int* __restrict__ rp, const int* __restrict__ bsum, int N){
  int i=blockIdx.x*blockDim.x+threadIdx.x;
  if(i<N) rp[i]+=bsum[i>>12];
}
__global__ void kscatterAll(EdgeTab et, int* __restrict__ RP, int* __restrict__ SRCS, int Etot){
  int i=blockIdx.x*blockDim.x+threadIdx.x;
  if(i>=Etot) return;
  int r=0;
  #pragma unroll
  for(int k=1;k<12;++k) r += (i>=et.seo[k]) ? 1 : 0;
  int e=i-et.seo[r];
  int d=iclamp(et.dst[r][e], et.nd[r]);
  int pos=atomicAdd(RP+et.rpo[r]+d,1);
  __builtin_nontemporal_store(iclamp(et.src[r][e], et.ns[r]), SRCS+pos);
}

// ---------- embeddings (+ fused layer-0 alphas) ----------
template<int D>
__global__ void kemb(const float* __restrict__ xin, const float* __restrict__ W,
                     const float* __restrict__ b, u16* __restrict__ xout, int N,
                     const float* __restrict__ WV0, f16* __restrict__ AA, GTab tab, int t){
  int n=blockIdx.x*blockDim.x+threadIdx.x;
  if(n>=N) return;
  float xr[D];
  #pragma unroll
  for(int k=0;k<D;++k) xr[k]=xin[(long)n*D+k];
  float o[64];
  u16* orow=xout+(long)n*64;
  #pragma unroll
  for(int j0=0;j0<64;j0+=8){
    #pragma unroll
    for(int jj=0;jj<8;++jj){
      float a=b[j0+jj];
      #pragma unroll
      for(int k=0;k<D;++k) a += xr[k]*W[k*64+j0+jj];
      o[j0+jj]=a;
    }
    uint4 pk;
    pk.x=(u32)f2bf(o[j0+0])|((u32)f2bf(o[j0+1])<<16);
    pk.y=(u32)f2bf(o[j0+2])|((u32)f2bf(o[j0+3])<<16);
    pk.z=(u32)f2bf(o[j0+4])|((u32)f2bf(o[j0+5])<<16);
    pk.w=(u32)f2bf(o[j0+6])|((u32)f2bf(o[j0+7])<<16);
    *(uint4*)(orow+j0)=pk;
  }
  int nr=tab.nrole[t];
  for(int ro=0;ro<nr;++ro){
    const float* wv=WV0+(size_t)tab.rwv[t][ro]*64;
    float acc=0.f;
    #pragma unroll
    for(int k=0;k<64;++k) acc += o[k]*wv[k];
    AA[tab.rofs[t][ro]+n]=(f16)acc;
  }
}

// ---------- merged alpha (layers 1,2) ----------
__global__ void kalphaM(const u16* __restrict__ X, const float* __restrict__ WVl,
                        f16* __restrict__ AA, GTab tab){
  __shared__ float wv[12*64];
  int b=blockIdx.x, tid=threadIdx.x;
  int ti=0;
  #pragma unroll
  for(int k=1;k<6;++k) ti += (b>=tab.abofs[k]) ? 1 : 0;
  int t=tab.tord[ti];
  int nr=tab.nrole[t];
  for(int i=tid;i<nr*64;i+=256){
    int ro=i>>6, j=i&63;
    wv[i]=WVl[tab.rwv[t][ro]*64+j];
  }
  __syncthreads();
  int nid=(b-tab.abofs[ti])*256+tid;
  if(nid>=tab.nn[t]) return;
  const u16* row=X+((long)tab.xo[t]+nid)*64;
  float xr[64];
  #pragma unroll
  for(int j=0;j<64;j+=8) unpack8(row+j,xr+j);
  for(int ro=0;ro<nr;++ro){
    float acc=0.f;
    #pragma unroll
    for(int k=0;k<64;++k) acc += xr[k]*wv[ro*64+k];
    AA[tab.rofs[t][ro]+nid]=(f16)acc;
  }
}

// ---------- per-role max over AA segments ----------
__global__ void kmg(const f16* __restrict__ AA, u32* __restrict__ MGl, GTab tab){
  const int NB=8;
  int b=blockIdx.x;
  int ro=b/NB, part=b%NB;
  int r=ro>>1, role=ro&1;
  int base,len;
  if(role==0){ base=tab.aso[r];           len=tab.nn[tab.rst[r]]; }
  else       { base=tab.dszb+tab.ado[r];  len=tab.nn[tab.rdt[r]]; }
  int i0=(int)((long)len*part/NB), i1=(int)((long)len*(part+1)/NB);
  float m=-3.4e38f;
  for(int i=i0+threadIdx.x;i<i1;i+=256) m=fmaxf(m,(float)AA[base+i]);
  #pragma unroll
  for(int off=32;off;off>>=1) m=fmaxf(m,__shfl_xor(m,off));
  __shared__ float red[4];
  if((threadIdx.x&63)==0) red[threadIdx.x>>6]=m;
  __syncthreads();
  if(threadIdx.x==0){
    float mm=fmaxf(fmaxf(red[0],red[1]),fmaxf(red[2],red[3]));
    atomicMax(MGl+ro,fenc(mm));
  }
}

// ---------- gather + WT-stage device helpers ----------
__device__ __forceinline__ void stage_wt(const u16* __restrict__ WTl, int r, int tid, char* wbuf){
  const uint4* s4=(const uint4*)(WTl+(size_t)r*4096);
  uint4 v0=s4[tid*2], v1=s4[tid*2+1];
  int b0=tid*32, j=b0>>7;
  *(uint4*)(wbuf+((b0   )^((j&7)<<4)))=v0;
  *(uint4*)(wbuf+((b0+16)^((j&7)<<4)))=v1;
}

__device__ __forceinline__ void gather_z(int r, int d, int Nt, int nid, int q,
                                         const f16* __restrict__ AA,
                                         const int* __restrict__ RP,
                                         const int* __restrict__ SRCS,
                                         const u16* __restrict__ Xc,
                                         const u32* __restrict__ MGl,
                                         const GTab& tab, char* zbuf){
  float msum=fdec2(MGl[r*2])+fdec2(MGl[r*2+1]);
  float m = msum>=0.f? msum : 0.2f*msum;
  float z[16];
  #pragma unroll
  for(int k=0;k<16;++k) z[k]=0.f;
  float sden=0.f;
  if(d<Nt){
    int b1=RP[tab.rpo[r]+d];
    int b0e= d? RP[tab.rpo[r]+d-1] : tab.seo[r];
    float adv=(float)AA[tab.dszb+tab.ado[r]+d];
    const u16* xbase=Xc+(long)tab.xo[tab.rst[r]]*64;
    const f16* asp=AA+tab.aso[r];
    int e=b0e;
    for(; e+1<b1; e+=2){
      int sr0=SRCS[e], sr1=SRCS[e+1];
      float ev0=(float)asp[sr0]+adv; ev0 = ev0>=0.f?ev0:0.2f*ev0;
      float ev1=(float)asp[sr1]+adv; ev1 = ev1>=0.f?ev1:0.2f*ev1;
      float p0=__expf(ev0-m), p1=__expf(ev1-m);
      const u16* rw0=xbase+(long)sr0*64+q*16;
      const u16* rw1=xbase+(long)sr1*64+q*16;
      uint4 a0=*(const uint4*)rw0;
      uint4 a1=*(const uint4*)(rw0+8);
      uint4 c0=*(const uint4*)rw1;
      uint4 c1=*(const uint4*)(rw1+8);
      sden+=p0+p1;
      float xr[8];
      unpack8((const u16*)&a0,xr);
      #pragma unroll
      for(int k=0;k<8;++k) z[k]+=p0*xr[k];
      unpack8((const u16*)&a1,xr);
      #pragma unroll
      for(int k=0;k<8;++k) z[8+k]+=p0*xr[k];
      unpack8((const u16*)&c0,xr);
      #pragma unroll
      for(int k=0;k<8;++k) z[k]+=p1*xr[k];
      unpack8((const u16*)&c1,xr);
      #pragma unroll
      for(int k=0;k<8;++k) z[8+k]+=p1*xr[k];
    }
    if(e<b1){
      int sr0=SRCS[e];
      float ev0=(float)asp[sr0]+adv; ev0 = ev0>=0.f?ev0:0.2f*ev0;
      float p0=__expf(ev0-m);
      const u16* rw0=xbase+(long)sr0*64+q*16;
      uint4 a0=*(const uint4*)rw0;
      uint4 a1=*(const uint4*)(rw0+8);
      sden+=p0;
      float xr[8];
      unpack8((const u16*)&a0,xr);
      #pragma unroll
      for(int k=0;k<8;++k) z[k]+=p0*xr[k];
      unpack8((const u16*)&a1,xr);
      #pragma unroll
      for(int k=0;k<8;++k) z[8+k]+=p0*xr[k];
    }
  }
  float inv=1.f/(sden+1e-16f);
  uint4 p0,p1;
  p0.x=(u32)f2bf(z[0]*inv) |((u32)f2bf(z[1]*inv)<<16);
  p0.y=(u32)f2bf(z[2]*inv) |((u32)f2bf(z[3]*inv)<<16);
  p0.z=(u32)f2bf(z[4]*inv) |((u32)f2bf(z[5]*inv)<<16);
  p0.w=(u32)f2bf(z[6]*inv) |((u32)f2bf(z[7]*inv)<<16);
  p1.x=(u32)f2bf(z[8]*inv) |((u32)f2bf(z[9]*inv)<<16);
  p1.y=(u32)f2bf(z[10]*inv)|((u32)f2bf(z[11]*inv)<<16);
  p1.z=(u32)f2bf(z[12]*inv)|((u32)f2bf(z[13]*inv)<<16);
  p1.w=(u32)f2bf(z[14]*inv)|((u32)f2bf(z[15]*inv)<<16);
  int zb=nid*128+q*32;
  *(uint4*)(zbuf+((zb   )^((nid&7)<<4)))=p0;
  *(uint4*)(zbuf+((zb+16)^((nid&7)<<4)))=p1;
}

// ---------- merged fused GAT (pipelined: gather_{r+1} || MFMA_r) ----------
__global__ void kfusedM2(const u16* __restrict__ Xc, u16* __restrict__ Xn,
                         const u16* __restrict__ WTl, const f16* __restrict__ AA,
                         const int* __restrict__ RP, const int* __restrict__ SRCS,
                         const float* __restrict__ BSl, const u32* __restrict__ MGl,
                         GTab tab){
  __shared__ char Lraw[32768];         // [ZB0|ZB1|WB0|WB1] 8KB each; C reuses [0,16K)
  char* L=(char*)Lraw;
  int tid=threadIdx.x;
  int b=blockIdx.x;
  int ti=0;
  #pragma unroll
  for(int k=1;k<6;++k) ti += (b>=tab.bofs[k]) ? 1 : 0;
  int t=tab.tord[ti];
  int d0=(b-tab.bofs[ti])*64;
  int Nt=tab.nn[t];
  int nid=tid>>2, q=tid&3;
  int d=d0+nid;

  f32x4 acc[4];
  #pragma unroll
  for(int ct=0;ct<4;++ct){ acc[ct][0]=0.f; acc[ct][1]=0.f; acc[ct][2]=0.f; acc[ct][3]=0.f; }

  int nrel=tab.nrel[t];
  gather_z(tab.rel[t][0],d,Nt,nid,q,AA,RP,SRCS,Xc,MGl,tab,L);
  stage_wt(WTl,tab.rel[t][0],tid,L+16384);
  __syncthreads();

  for(int ri=0;ri<nrel;++ri){
    int zcur = (ri&1)? 8192 : 0;
    int wcur = 16384 + zcur;
    if(ri+1<nrel){
      int znxt = (ri&1)? 0 : 8192;
      gather_z(tab.rel[t][ri+1],d,Nt,nid,q,AA,RP,SRCS,Xc,MGl,tab,L+znxt);
      stage_wt(WTl,tab.rel[t][ri+1],tid,L+16384+znxt);
    }
    {
      int w=tid>>6, l=tid&63;
      int nt=w*16;
      int arow=nt+(l&15);
      int kb=(l>>4)*8;
      #pragma unroll
      for(int ks=0;ks<64;ks+=32){
        int ab=arow*128+(ks+kb)*2;
        uint4 av=*(uint4*)(L+zcur+(ab^((arow&7)<<4)));
        bf16x8 af=*(bf16x8*)&av;
        #pragma unroll
        for(int ct=0;ct<4;++ct){
          int jrow=ct*16+(l&15);
          int bb=jrow*128+(ks+kb)*2;
          uint4 bv=*(uint4*)(L+wcur+(bb^((jrow&7)<<4)));
          bf16x8 bfr=*(bf16x8*)&bv;
          acc[ct]=__builtin_amdgcn_mfma_f32_16x16x32_bf16(af,bfr,acc[ct],0,0,0);
        }
      }
    }
    __syncthreads();
  }

  // C -> LDS (reuse [0,16K))
  {
    int w=tid>>6, l=tid&63;
    int nt=w*16;
    #pragma unroll
    for(int ct=0;ct<4;++ct){
      #pragma unroll
      for(int r4=0;r4<4;++r4){
        int crow=nt+(l>>4)*4+r4;
        int ccol=ct*16+(l&15);
        int cb=crow*256+ccol*4;
        *(float*)(L+(cb^((crow&7)<<4)))=acc[ct][r4];
      }
    }
  }
  __syncthreads();
  // epilogue: bias + relu + nontemporal bf16 write (avoid evicting Xc from L3)
  {
    int nn=tid>>2, cq=tid&3;
    if(d0+nn<Nt){
      float cv[16];
      #pragma unroll
      for(int p=0;p<4;++p){
        int cb=nn*256+cq*64+p*16;
        uint4 v=*(uint4*)(L+(cb^((nn&7)<<4)));
        const float* f=(const float*)&v;
        cv[p*4+0]=f[0]; cv[p*4+1]=f[1]; cv[p*4+2]=f[2]; cv[p*4+3]=f[3];
      }
      const float* bs=BSl+t*64+cq*16;
      u32 wd[8];
      #pragma unroll
      for(int i=0;i<8;++i){
        float lo=fmaxf(cv[2*i]  +bs[2*i],  0.f);
        float hi=fmaxf(cv[2*i+1]+bs[2*i+1],0.f);
        wd[i]=(u32)f2bf(lo)|((u32)f2bf(hi)<<16);
      }
      u16* orow=Xn+((long)tab.xo[t]+d0+nn)*64+cq*16;
      u32x4 s0; s0.x=wd[0]; s0.y=wd[1]; s0.z=wd[2]; s0.w=wd[3];
      u32x4 s1; s1.x=wd[4]; s1.y=wd[5]; s1.z=wd[6]; s1.w=wd[7];
      __builtin_nontemporal_store(s0, (u32x4*)orow);
      __builtin_nontemporal_store(s1, (u32x4*)(orow+8));
    }
  }
}

// classifier
__global__ void kcls(const u16* __restrict__ tx, const float* __restrict__ W1,
                     const float* __restrict__ b1, const float* __restrict__ W2,
                     const float* __restrict__ b2, float* __restrict__ out, int N){
  int n=blockIdx.x*blockDim.x+threadIdx.x;
  if(n>=N) return;
  const u16* row=tx+(long)n*64;
  float xr[64];
  #pragma unroll
  for(int j=0;j<64;j+=8) unpack8(row+j,xr+j);
  float acc2=0.f;
  for(int j=0;j<64;++j){
    float a=b1[j];
    #pragma unroll
    for(int k=0;k<64;++k) a += xr[k]*W1[k*64+j];
    a=fmaxf(a,0.f);
    acc2 += a*W2[j];
  }
  float zv=acc2+b2[0];
  out[n]=1.f/(1.f+__expf(-zv));
}

// ---------- pooling ----------
__global__ void kgrp(const int* __restrict__ batch, int* __restrict__ grp, int N){
  int g=blockIdx.x*blockDim.x+threadIdx.x;
  if(g>1024) return;
  if(g==1024){ grp[1024]=N; return; }
  int lo=0, hi=N;
  while(lo<hi){ int mid=(lo+hi)>>1; if(batch[mid]<g) lo=mid+1; else hi=mid; }
  grp[g]=lo;
}
__global__ void kpoolf(const u16* __restrict__ tx, const int* __restrict__ grp,
                       const float* __restrict__ pW, const float* __restrict__ pb,
                       float* __restrict__ out){
  __shared__ float S[256], M[256], V[128];
  int g=blockIdx.x, t=threadIdx.x, w=t>>6, j=t&63;
  int n0=grp[g], n1=grp[g+1];
  float s=0.f, m=-3.4e38f;
  for(int n=n0+w; n<n1; n+=4){
    float v=bf2f(tx[(long)n*64+j]);
    s+=v; m=fmaxf(m,v);
  }
  S[t]=s; M[t]=m; __syncthreads();
  if(t<64){
    float ss=S[t]+S[t+64]+S[t+128]+S[t+192];
    float mm=fmaxf(fmaxf(M[t],M[t+64]),fmaxf(M[t+128],M[t+192]));
    int cnt=n1-n0;
    V[t]=ss/fmaxf((float)cnt,1.f);
    V[64+t]=(cnt>0)?mm:0.f;
  }
  __syncthreads();
  if(t<64){
    float acc=pb[t];
    for(int k=0;k<128;++k) acc+=V[k]*pW[k*64+t];
    out[(long)g*64+t]=acc;
  }
}

// ---------- host ----------
extern "C" void kernel_launch(void* const* d_in, const int* in_sizes, int n_in,
                              void* d_out, int out_size, void* d_ws, size_t ws_size,
                              hipStream_t stream){
  const int   NN[6]={100000,150000,500000,20000,5000,50000};
  const long  XO[6]={0,100000,250000,750000,770000,775000};
  const int   RS[12]={0,1,2,2,2,2,1,2,3,4,5,2};
  const int   RD[12]={1,2,3,4,5,2,0,1,2,2,2,2};
  const int   EC[12]={150000,500000,500000,500000,500000,500000,150000,500000,500000,500000,500000,500000};

  const float* xin[6];  for(int t=0;t<6;++t) xin[t]=(const float*)d_in[t];
  const float* embW[6]; const float* embB[6];
  for(int t=0;t<6;++t){ embW[t]=(const float*)d_in[6+2*t]; embB[t]=(const float*)d_in[7+2*t]; }
  const float* gatW =(const float*)d_in[18];
  const float* gatAs=(const float*)d_in[19];
  const float* gatAd=(const float*)d_in[20];
  const float* gatB =(const float*)d_in[21];
  const float* poolW=(const float*)d_in[22];
  const float* poolB=(const float*)d_in[23];
  const float* W1=(const float*)d_in[24];
  const float* b1=(const float*)d_in[25];
  const float* W2=(const float*)d_in[26];
  const float* b2=(const float*)d_in[27];
  const int* esrc[12]; const int* edst[12];
  for(int r=0;r<12;++r){ esrc[r]=(const int*)d_in[28+2*r]; edst[r]=(const int*)d_in[29+2*r]; }
  const int* batch=(const int*)d_in[52];
  float* out=(float*)d_out;
  (void)in_sizes; (void)n_in;

  EdgeTab et;
  GTab tab;
  int rpo=0, seo=0, asz=0, dsz=0;
  for(int r=0;r<12;++r){
    et.dst[r]=edst[r]; et.src[r]=esrc[r];
    et.seo[r]=seo; et.rpo[r]=rpo;
    et.nd[r]=NN[RD[r]]; et.ns[r]=NN[RS[r]];
    tab.rst[r]=RS[r]; tab.rdt[r]=RD[r];
    tab.seo[r]=seo; tab.rpo[r]=rpo;
    tab.aso[r]=asz; tab.ado[r]=dsz;
    seo+=EC[r]; rpo+=NN[RD[r]]+1;
    asz+=NN[RS[r]]; dsz+=NN[RD[r]];
  }
  et.seo[12]=seo; et.rpo[12]=rpo;
  const int Etot=seo;
  const int RPtot=rpo;
  tab.dszb=asz;
  for(int t=0;t<6;++t){ tab.nn[t]=NN[t]; tab.xo[t]=(int)XO[t]; }
  const int TORD[6]={4,3,5,2,1,0};
  int bo=0, abo=0;
  for(int i=0;i<6;++i){
    int t=TORD[i];
    tab.tord[i]=t;
    tab.bofs[i]=bo;   bo+=CDIV(NN[t],64);
    tab.abofs[i]=abo; abo+=CDIV(NN[t],256);
  }
  tab.bofs[6]=bo; tab.abofs[6]=abo;
  for(int t=0;t<6;++t){ tab.nrel[t]=0; tab.nrole[t]=0; }
  for(int r=0;r<12;++r){
    int dt=RD[r];
    tab.rel[dt][tab.nrel[dt]++]=r;
    int st=RS[r];
    tab.rwv[st][tab.nrole[st]]=r*2+0;   tab.rofs[st][tab.nrole[st]++]=tab.aso[r];
    tab.rwv[dt][tab.nrole[dt]]=r*2+1;   tab.rofs[dt][tab.nrole[dt]++]=asz+tab.ado[r];
  }

  // ---- workspace ----
  char* w=(char*)d_ws;
  size_t off=0;
  auto take=[&](size_t bytes)->void*{
    void* p=w+off; off+=(bytes+(size_t)255)&~(size_t)255; return p;
  };
  u16*   X1   =(u16*)  take(105600000);
  u16*   X2   =(u16*)  take(105600000);
  int*   RP   =(int*)  take((size_t)RPtot*4);
  int*   SRCS =(int*)  take((size_t)Etot*4);
  int*   BS   =(int*)  take(4096);
  f16*   AA   =(f16*)  take((size_t)(asz+dsz)*2);
  float* WV   =(float*)take(72*64*4);
  float* BSUM =(float*)take(4608);
  int*   GRP  =(int*)  take(4104);
  u16*   WT   =(u16*)  take(294912);
  u32*   MG   =(u32*)  take(288);
  size_t need=off;

  const int B=256;

  if(ws_size<need){
    kdiag<<<CDIV(out_size,B),B,0,stream>>>(out,out_size,(float)(ws_size>>20));
    return;
  }

  // weight prep (kwv also zeroes MG)
  kwconv<<<CDIV(147456,B),B,0,stream>>>(gatW,WT,147456);
  kwv<<<72,64,0,stream>>>(gatW,gatAs,gatAd,WV,MG);
  kbsum<<<18,64,0,stream>>>(gatB,BSUM);

  // CSR build: single-pass hist + scan + single-pass scatter
  int nbs=CDIV(RPtot,4096);
  kzeroi<<<CDIV(RPtot,B),B,0,stream>>>(RP,RPtot);
  khistAll<<<CDIV(Etot,B),B,0,stream>>>(et,RP,Etot);
  kscan1<<<nbs,256,0,stream>>>(RP,RP,BS,RPtot);
  kscan2b<<<1,256,0,stream>>>(BS,nbs);
  kscan3<<<CDIV(RPtot,B),B,0,stream>>>(RP,BS,RPtot);
  kscatterAll<<<CDIV(Etot,B),B,0,stream>>>(et,RP,SRCS,Etot);

  // embeddings (+ layer-0 alphas) -> X1
  kemb< 8><<<CDIV(NN[0],B),B,0,stream>>>(xin[0],embW[0],embB[0],X1+XO[0]*64,NN[0],WV,AA,tab,0);
  kemb< 6><<<CDIV(NN[1],B),B,0,stream>>>(xin[1],embW[1],embB[1],X1+XO[1]*64,NN[1],WV,AA,tab,1);
  kemb<12><<<CDIV(NN[2],B),B,0,stream>>>(xin[2],embW[2],embB[2],X1+XO[2]*64,NN[2],WV,AA,tab,2);
  kemb< 6><<<CDIV(NN[3],B),B,0,stream>>>(xin[3],embW[3],embB[3],X1+XO[3]*64,NN[3],WV,AA,tab,3);
  kemb< 5><<<CDIV(NN[4],B),B,0,stream>>>(xin[4],embW[4],embB[4],X1+XO[4]*64,NN[4],WV,AA,tab,4);
  kemb< 5><<<CDIV(NN[5],B),B,0,stream>>>(xin[5],embW[5],embB[5],X1+XO[5]*64,NN[5],WV,AA,tab,5);

  u16* Xc=X1; u16* Xn=X2;
  for(int l=0;l<3;++l){
    if(l>0) kalphaM<<<abo,256,0,stream>>>(Xc,WV+(size_t)l*1536,AA,tab);
    kmg<<<24*8,256,0,stream>>>(AA,MG+(size_t)l*24,tab);
    kfusedM2<<<bo,256,0,stream>>>(Xc,Xn,WT+(size_t)l*49152,AA,RP,SRCS,
                                  BSUM+(size_t)l*384,MG+(size_t)l*24,tab);
    u16* tmp=Xc; Xc=Xn; Xn=tmp;
  }

  kcls<<<CDIV(NN[2],B),B,0,stream>>>(Xc+XO[2]*64,W1,b1,W2,b2,out,NN[2]);

  kgrp<<<CDIV(1025,B),B,0,stream>>>(batch,GRP,NN[2]);
  kpoolf<<<1024,256,0,stream>>>(Xc+XO[2]*64,GRP,poolW,poolB,out+500000);
}

// Round 19
// 2266.557 us; speedup vs baseline: 1.0275x; 1.0206x over previous
//
#include <hip/hip_runtime.h>
#include <hip/hip_bf16.h>

typedef unsigned int u32;
typedef unsigned short u16;
typedef _Float16 f16;
typedef float f32x4 __attribute__((ext_vector_type(4)));
typedef short bf16x8 __attribute__((ext_vector_type(8)));
typedef unsigned int u32x4 __attribute__((ext_vector_type(4)));

#define CDIV(a,b) (((a)+(b)-1)/(b))

// ---------- helpers ----------
__device__ __forceinline__ float bf2f(u32 h){ return __uint_as_float(h<<16); }
__device__ __forceinline__ u16 f2bf(float f){
  u32 u=__float_as_uint(f);
  return (u16)((u + 0x7fffu + ((u>>16)&1u))>>16);   // RNE
}
__device__ __forceinline__ u32 fenc(float f){
  u32 u=__float_as_uint(f);
  return (u&0x80000000u)?~u:(u|0x80000000u);
}
__device__ __forceinline__ float fdec2(u32 e){
  u32 u=(e&0x80000000u)?(e&0x7fffffffu):~e;
  return __uint_as_float(u);
}
__device__ __forceinline__ void unpack8(const u16* p, float* xr){
  uint4 v=*(const uint4*)p;
  xr[0]=bf2f(v.x&0xffffu); xr[1]=bf2f(v.x>>16);
  xr[2]=bf2f(v.y&0xffffu); xr[3]=bf2f(v.y>>16);
  xr[4]=bf2f(v.z&0xffffu); xr[5]=bf2f(v.z>>16);
  xr[6]=bf2f(v.w&0xffffu); xr[7]=bf2f(v.w>>16);
}
__device__ __forceinline__ int iclamp(int i, int n){
  unsigned u=(unsigned)i; return (u>=(unsigned)n)?0:i;
}

struct EdgeTab {
  const int* dst[12];
  const int* src[12];
  int seo[13];
  int rpo[13];
  int nd[12];
  int ns[12];
};

struct GTab {
  int nn[6]; int xo[6];
  int rst[12]; int rdt[12];
  int aso[12], ado[12], rpo[12], seo[12];
  int tord[6]; int bofs[7];
  int abofs[7];
  int nrel[6], rel[6][6];
  int nrole[6]; int rwv[6][12]; int rofs[6][12];
  int dszb;
};

// ---------- misc ----------
__global__ void kdiag(float* out, int n, float v){
  int i=blockIdx.x*blockDim.x+threadIdx.x;
  if(i<n) out[i]=(i==0)?v:0.f;
}
__global__ void kzeroi(int* p, int n){
  int i=blockIdx.x*blockDim.x+threadIdx.x;
  if(i<n) p[i]=0;
}
__global__ void kbsum(const float* __restrict__ gb, float* __restrict__ bsum){
  int l=blockIdx.x/6, t=blockIdx.x%6, j=threadIdx.x;
  const int rd[12]={1,2,3,4,5,2,0,1,2,2,2,2};
  float a=0.f;
  #pragma unroll
  for(int r=0;r<12;++r) if(rd[r]==t) a += gb[(l*12+r)*64 + j];
  bsum[(l*6+t)*64 + j]=a;
}
__global__ void kwconv(const float* __restrict__ gw, u16* __restrict__ wt, int total){
  int o=blockIdx.x*blockDim.x+threadIdx.x;
  if(o>=total) return;
  int m=o>>12, rem=o&4095, j=rem>>6, k=rem&63;
  wt[o]=f2bf(gw[(m<<12)+(k<<6)+j]);
}
// wv vectors; also zeroes MG
__global__ void kwv(const float* __restrict__ gw, const float* __restrict__ gas,
                    const float* __restrict__ gad, float* __restrict__ wv,
                    u32* __restrict__ MG){
  int m=blockIdx.x;
  int lr=m>>1, role=m&1;
  int k=threadIdx.x;
  if(k==0){
    int l=lr/12, r=lr%12;
    MG[l*24+r*2+role]=0u;
  }
  const float* a=(role?gad:gas)+(size_t)lr*64;
  const float* W=gw+(size_t)lr*4096;
  float acc=0.f;
  for(int j=0;j<64;++j) acc += W[k*64+j]*a[j];
  wv[(size_t)m*64+k]=acc;
}

// ---------- CSR build (single-pass) ----------
__global__ void khistAll(EdgeTab et, int* __restrict__ RP, int Etot){
  int i=blockIdx.x*blockDim.x+threadIdx.x;
  if(i>=Etot) return;
  int r=0;
  #pragma unroll
  for(int k=1;k<12;++k) r += (i>=et.seo[k]) ? 1 : 0;
  int e=i-et.seo[r];
  int d=iclamp(et.dst[r][e], et.nd[r]);
  atomicAdd(RP+et.rpo[r]+d,1);
}
__global__ void kscan1(const int* __restrict__ hist, int* __restrict__ rp, int* __restrict__ bsum, int N){
  __shared__ int lds[256];
  __shared__ int pref[256];
  int b=blockIdx.x, t=threadIdx.x;
  int base=b*4096+t*16;
  int v[16]; int s=0;
  #pragma unroll
  for(int k=0;k<16;++k){ int idx=base+k; v[k]=(idx<N)?hist[idx]:0; s+=v[k]; }
  lds[t]=s; __syncthreads();
  if(t==0){ int run=0; for(int i=0;i<256;++i){ pref[i]=run; run+=lds[i]; } bsum[b]=run; }
  __syncthreads();
  int run=pref[t];
  #pragma unroll
  for(int k=0;k<16;++k){ int idx=base+k; if(idx<N) rp[idx]=run; run+=v[k]; }
}
__global__ void kscan2b(int* bsum, int nb){
  __shared__ int lds[256], pref[256], tot;
  int t=threadIdx.x;
  int v[4]; int s=0;
  #pragma unroll
  for(int k=0;k<4;++k){ int idx=t*4+k; v[k]=(idx<nb)?bsum[idx]:0; s+=v[k]; }
  lds[t]=s; __syncthreads();
  if(t==0){ int run=0; for(int i=0;i<256;++i){ pref[i]=run; run+=lds[i]; } tot=run; }
  __syncthreads();
  int run=pref[t];
  #pragma unroll
  for(int k=0;k<4;++k){ int idx=t*4+k; if(idx<nb){ int x=v[k]; bsum[idx]=run; run+=x; } }
  if(t==0) bsum[nb]=tot;
}
__global__ void kscan3(int* __restrict__ rp, const int* __restrict__ bsum, int N){
  int i=blockIdx.x*blockDim.x+threadIdx.x;
  if(i<N) rp[i]+=bsum[i>>12];
}
__global__ void kscatterAll(EdgeTab et, int* __restrict__ RP, int* __restrict__ SRCS, int Etot){
  int i=blockIdx.x*blockDim.x+threadIdx.x;
  if(i>=Etot) return;
  int r=0;
  #pragma unroll
  for(int k=1;k<12;++k) r += (i>=et.seo[k]) ? 1 : 0;
  int e=i-et.seo[r];
  int d=iclamp(et.dst[r][e], et.nd[r]);
  int pos=atomicAdd(RP+et.rpo[r]+d,1);
  SRCS[pos]=iclamp(et.src[r][e], et.ns[r]);
}

// ---------- embeddings (+ fused layer-0 alphas) ----------
template<int D>
__global__ void kemb(const float* __restrict__ xin, const float* __restrict__ W,
                     const float* __restrict__ b, u16* __restrict__ xout, int N,
                     const float* __restrict__ WV0, f16* __restrict__ AA, GTab tab, int t){
  int n=blockIdx.x*blockDim.x+threadIdx.x;
  if(n>=N) return;
  float xr[D];
  #pragma unroll
  for(int k=0;k<D;++k) xr[k]=xin[(long)n*D+k];
  float o[64];
  u16* orow=xout+(long)n*64;
  #pragma unroll
  for(int j0=0;j0<64;j0+=8){
    #pragma unroll
    for(int jj=0;jj<8;++jj){
      float a=b[j0+jj];
      #pragma unroll
      for(int k=0;k<D;++k) a += xr[k]*W[k*64+j0+jj];
      o[j0+jj]=a;
    }
    uint4 pk;
    pk.x=(u32)f2bf(o[j0+0])|((u32)f2bf(o[j0+1])<<16);
    pk.y=(u32)f2bf(o[j0+2])|((u32)f2bf(o[j0+3])<<16);
    pk.z=(u32)f2bf(o[j0+4])|((u32)f2bf(o[j0+5])<<16);
    pk.w=(u32)f2bf(o[j0+6])|((u32)f2bf(o[j0+7])<<16);
    *(uint4*)(orow+j0)=pk;
  }
  int nr=tab.nrole[t];
  for(int ro=0;ro<nr;++ro){
    const float* wv=WV0+(size_t)tab.rwv[t][ro]*64;
    float acc=0.f;
    #pragma unroll
    for(int k=0;k<64;++k) acc += o[k]*wv[k];
    AA[tab.rofs[t][ro]+n]=(f16)acc;
  }
}

// ---------- merged alpha (layers 1,2) ----------
__global__ void kalphaM(const u16* __restrict__ X, const float* __restrict__ WVl,
                        f16* __restrict__ AA, GTab tab){
  __shared__ float wv[12*64];
  int b=blockIdx.x, tid=threadIdx.x;
  int ti=0;
  #pragma unroll
  for(int k=1;k<6;++k) ti += (b>=tab.abofs[k]) ? 1 : 0;
  int t=tab.tord[ti];
  int nr=tab.nrole[t];
  for(int i=tid;i<nr*64;i+=256){
    int ro=i>>6, j=i&63;
    wv[i]=WVl[tab.rwv[t][ro]*64+j];
  }
  __syncthreads();
  int nid=(b-tab.abofs[ti])*256+tid;
  if(nid>=tab.nn[t]) return;
  const u16* row=X+((long)tab.xo[t]+nid)*64;
  float xr[64];
  #pragma unroll
  for(int j=0;j<64;j+=8) unpack8(row+j,xr+j);
  for(int ro=0;ro<nr;++ro){
    float acc=0.f;
    #pragma unroll
    for(int k=0;k<64;++k) acc += xr[k]*wv[ro*64+k];
    AA[tab.rofs[t][ro]+nid]=(f16)acc;
  }
}

// ---------- per-role max over AA segments ----------
__global__ void kmg(const f16* __restrict__ AA, u32* __restrict__ MGl, GTab tab){
  const int NB=8;
  int b=blockIdx.x;
  int ro=b/NB, part=b%NB;
  int r=ro>>1, role=ro&1;
  int base,len;
  if(role==0){ base=tab.aso[r];           len=tab.nn[tab.rst[r]]; }
  else       { base=tab.dszb+tab.ado[r];  len=tab.nn[tab.rdt[r]]; }
  int i0=(int)((long)len*part/NB), i1=(int)((long)len*(part+1)/NB);
  float m=-3.4e38f;
  for(int i=i0+threadIdx.x;i<i1;i+=256) m=fmaxf(m,(float)AA[base+i]);
  #pragma unroll
  for(int off=32;off;off>>=1) m=fmaxf(m,__shfl_xor(m,off));
  __shared__ float red[4];
  if((threadIdx.x&63)==0) red[threadIdx.x>>6]=m;
  __syncthreads();
  if(threadIdx.x==0){
    float mm=fmaxf(fmaxf(red[0],red[1]),fmaxf(red[2],red[3]));
    atomicMax(MGl+ro,fenc(mm));
  }
}

// ---------- gather + WT-stage device helpers ----------
__device__ __forceinline__ void stage_wt(const u16* __restrict__ WTl, int r, int tid, char* wbuf){
  const uint4* s4=(const uint4*)(WTl+(size_t)r*4096);
  uint4 v0=s4[tid*2], v1=s4[tid*2+1];
  int b0=tid*32, j=b0>>7;
  *(uint4*)(wbuf+((b0   )^((j&7)<<4)))=v0;
  *(uint4*)(wbuf+((b0+16)^((j&7)<<4)))=v1;
}

__device__ __forceinline__ void gather_z(int r, int d, int Nt, int nid, int q,
                                         const f16* __restrict__ AA,
                                         const int* __restrict__ RP,
                                         const int* __restrict__ SRCS,
                                         const u16* __restrict__ Xc,
                                         const u32* __restrict__ MGl,
                                         const GTab& tab, char* zbuf){
  float msum=fdec2(MGl[r*2])+fdec2(MGl[r*2+1]);
  float m = msum>=0.f? msum : 0.2f*msum;
  float z[16];
  #pragma unroll
  for(int k=0;k<16;++k) z[k]=0.f;
  float sden=0.f;
  if(d<Nt){
    int b1=RP[tab.rpo[r]+d];
    int b0e= d? RP[tab.rpo[r]+d-1] : tab.seo[r];
    float adv=(float)AA[tab.dszb+tab.ado[r]+d];
    const u16* xbase=Xc+(long)tab.xo[tab.rst[r]]*64;
    const f16* asp=AA+tab.aso[r];
    int e=b0e;
    for(; e+1<b1; e+=2){
      int sr0=SRCS[e], sr1=SRCS[e+1];
      float ev0=(float)asp[sr0]+adv; ev0 = ev0>=0.f?ev0:0.2f*ev0;
      float ev1=(float)asp[sr1]+adv; ev1 = ev1>=0.f?ev1:0.2f*ev1;
      float p0=__expf(ev0-m), p1=__expf(ev1-m);
      const u16* rw0=xbase+(long)sr0*64+q*16;
      const u16* rw1=xbase+(long)sr1*64+q*16;
      uint4 a0=*(const uint4*)rw0;
      uint4 a1=*(const uint4*)(rw0+8);
      uint4 c0=*(const uint4*)rw1;
      uint4 c1=*(const uint4*)(rw1+8);
      sden+=p0+p1;
      float xr[8];
      unpack8((const u16*)&a0,xr);
      #pragma unroll
      for(int k=0;k<8;++k) z[k]+=p0*xr[k];
      unpack8((const u16*)&a1,xr);
      #pragma unroll
      for(int k=0;k<8;++k) z[8+k]+=p0*xr[k];
      unpack8((const u16*)&c0,xr);
      #pragma unroll
      for(int k=0;k<8;++k) z[k]+=p1*xr[k];
      unpack8((const u16*)&c1,xr);
      #pragma unroll
      for(int k=0;k<8;++k) z[8+k]+=p1*xr[k];
    }
    if(e<b1){
      int sr0=SRCS[e];
      float ev0=(float)asp[sr0]+adv; ev0 = ev0>=0.f?ev0:0.2f*ev0;
      float p0=__expf(ev0-m);
      const u16* rw0=xbase+(long)sr0*64+q*16;
      uint4 a0=*(const uint4*)rw0;
      uint4 a1=*(const uint4*)(rw0+8);
      sden+=p0;
      float xr[8];
      unpack8((const u16*)&a0,xr);
      #pragma unroll
      for(int k=0;k<8;++k) z[k]+=p0*xr[k];
      unpack8((const u16*)&a1,xr);
      #pragma unroll
      for(int k=0;k<8;++k) z[8+k]+=p0*xr[k];
    }
  }
  float inv=1.f/(sden+1e-16f);
  uint4 p0,p1;
  p0.x=(u32)f2bf(z[0]*inv) |((u32)f2bf(z[1]*inv)<<16);
  p0.y=(u32)f2bf(z[2]*inv) |((u32)f2bf(z[3]*inv)<<16);
  p0.z=(u32)f2bf(z[4]*inv) |((u32)f2bf(z[5]*inv)<<16);
  p0.w=(u32)f2bf(z[6]*inv) |((u32)f2bf(z[7]*inv)<<16);
  p1.x=(u32)f2bf(z[8]*inv) |((u32)f2bf(z[9]*inv)<<16);
  p1.y=(u32)f2bf(z[10]*inv)|((u32)f2bf(z[11]*inv)<<16);
  p1.z=(u32)f2bf(z[12]*inv)|((u32)f2bf(z[13]*inv)<<16);
  p1.w=(u32)f2bf(z[14]*inv)|((u32)f2bf(z[15]*inv)<<16);
  int zb=nid*128+q*32;
  *(uint4*)(zbuf+((zb   )^((nid&7)<<4)))=p0;
  *(uint4*)(zbuf+((zb+16)^((nid&7)<<4)))=p1;
}

// ---------- merged fused GAT (pipelined: gather_{r+1} || MFMA_r) ----------
__global__ void kfusedM2(const u16* __restrict__ Xc, u16* __restrict__ Xn,
                         const u16* __restrict__ WTl, const f16* __restrict__ AA,
                         const int* __restrict__ RP, const int* __restrict__ SRCS,
                         const float* __restrict__ BSl, const u32* __restrict__ MGl,
                         GTab tab){
  __shared__ char Lraw[32768];         // [ZB0|ZB1|WB0|WB1] 8KB each; C reuses [0,16K)
  char* L=(char*)Lraw;
  int tid=threadIdx.x;
  int b=blockIdx.x;
  int ti=0;
  #pragma unroll
  for(int k=1;k<6;++k) ti += (b>=tab.bofs[k]) ? 1 : 0;
  int t=tab.tord[ti];
  int d0=(b-tab.bofs[ti])*64;
  int Nt=tab.nn[t];
  int nid=tid>>2, q=tid&3;
  int d=d0+nid;

  f32x4 acc[4];
  #pragma unroll
  for(int ct=0;ct<4;++ct){ acc[ct][0]=0.f; acc[ct][1]=0.f; acc[ct][2]=0.f; acc[ct][3]=0.f; }

  int nrel=tab.nrel[t];
  gather_z(tab.rel[t][0],d,Nt,nid,q,AA,RP,SRCS,Xc,MGl,tab,L);
  stage_wt(WTl,tab.rel[t][0],tid,L+16384);
  __syncthreads();

  for(int ri=0;ri<nrel;++ri){
    int zcur = (ri&1)? 8192 : 0;
    int wcur = 16384 + zcur;
    if(ri+1<nrel){
      int znxt = (ri&1)? 0 : 8192;
      gather_z(tab.rel[t][ri+1],d,Nt,nid,q,AA,RP,SRCS,Xc,MGl,tab,L+znxt);
      stage_wt(WTl,tab.rel[t][ri+1],tid,L+16384+znxt);
    }
    {
      int w=tid>>6, l=tid&63;
      int nt=w*16;
      int arow=nt+(l&15);
      int kb=(l>>4)*8;
      #pragma unroll
      for(int ks=0;ks<64;ks+=32){
        int ab=arow*128+(ks+kb)*2;
        uint4 av=*(uint4*)(L+zcur+(ab^((arow&7)<<4)));
        bf16x8 af=*(bf16x8*)&av;
        #pragma unroll
        for(int ct=0;ct<4;++ct){
          int jrow=ct*16+(l&15);
          int bb=jrow*128+(ks+kb)*2;
          uint4 bv=*(uint4*)(L+wcur+(bb^((jrow&7)<<4)));
          bf16x8 bfr=*(bf16x8*)&bv;
          acc[ct]=__builtin_amdgcn_mfma_f32_16x16x32_bf16(af,bfr,acc[ct],0,0,0);
        }
      }
    }
    __syncthreads();
  }

  // C -> LDS (reuse [0,16K))
  {
    int w=tid>>6, l=tid&63;
    int nt=w*16;
    #pragma unroll
    for(int ct=0;ct<4;++ct){
      #pragma unroll
      for(int r4=0;r4<4;++r4){
        int crow=nt+(l>>4)*4+r4;
        int ccol=ct*16+(l&15);
        int cb=crow*256+ccol*4;
        *(float*)(L+(cb^((crow&7)<<4)))=acc[ct][r4];
      }
    }
  }
  __syncthreads();
  // epilogue: bias + relu + nontemporal bf16 write
  {
    int nn=tid>>2, cq=tid&3;
    if(d0+nn<Nt){
      float cv[16];
      #pragma unroll
      for(int p=0;p<4;++p){
        int cb=nn*256+cq*64+p*16;
        uint4 v=*(uint4*)(L+(cb^((nn&7)<<4)));
        const float* f=(const float*)&v;
        cv[p*4+0]=f[0]; cv[p*4+1]=f[1]; cv[p*4+2]=f[2]; cv[p*4+3]=f[3];
      }
      const float* bs=BSl+t*64+cq*16;
      u32 wd[8];
      #pragma unroll
      for(int i=0;i<8;++i){
        float lo=fmaxf(cv[2*i]  +bs[2*i],  0.f);
        float hi=fmaxf(cv[2*i+1]+bs[2*i+1],0.f);
        wd[i]=(u32)f2bf(lo)|((u32)f2bf(hi)<<16);
      }
      u16* orow=Xn+((long)tab.xo[t]+d0+nn)*64+cq*16;
      u32x4 s0; s0.x=wd[0]; s0.y=wd[1]; s0.z=wd[2]; s0.w=wd[3];
      u32x4 s1; s1.x=wd[4]; s1.y=wd[5]; s1.z=wd[6]; s1.w=wd[7];
      __builtin_nontemporal_store(s0, (u32x4*)orow);
      __builtin_nontemporal_store(s1, (u32x4*)(orow+8));
    }
  }
}

// classifier
__global__ void kcls(const u16* __restrict__ tx, const float* __restrict__ W1,
                     const float* __restrict__ b1, const float* __restrict__ W2,
                     const float* __restrict__ b2, float* __restrict__ out, int N){
  int n=blockIdx.x*blockDim.x+threadIdx.x;
  if(n>=N) return;
  const u16* row=tx+(long)n*64;
  float xr[64];
  #pragma unroll
  for(int j=0;j<64;j+=8) unpack8(row+j,xr+j);
  float acc2=0.f;
  for(int j=0;j<64;++j){
    float a=b1[j];
    #pragma unroll
    for(int k=0;k<64;++k) a += xr[k]*W1[k*64+j];
    a=fmaxf(a,0.f);
    acc2 += a*W2[j];
  }
  float zv=acc2+b2[0];
  out[n]=1.f/(1.f+__expf(-zv));
}

// ---------- pooling ----------
__global__ void kgrp(const int* __restrict__ batch, int* __restrict__ grp, int N){
  int g=blockIdx.x*blockDim.x+threadIdx.x;
  if(g>1024) return;
  if(g==1024){ grp[1024]=N; return; }
  int lo=0, hi=N;
  while(lo<hi){ int mid=(lo+hi)>>1; if(batch[mid]<g) lo=mid+1; else hi=mid; }
  grp[g]=lo;
}
__global__ void kpoolf(const u16* __restrict__ tx, const int* __restrict__ grp,
                       const float* __restrict__ pW, const float* __restrict__ pb,
                       float* __restrict__ out){
  __shared__ float S[256], M[256], V[128];
  int g=blockIdx.x, t=threadIdx.x, w=t>>6, j=t&63;
  int n0=grp[g], n1=grp[g+1];
  float s=0.f, m=-3.4e38f;
  for(int n=n0+w; n<n1; n+=4){
    float v=bf2f(tx[(long)n*64+j]);
    s+=v; m=fmaxf(m,v);
  }
  S[t]=s; M[t]=m; __syncthreads();
  if(t<64){
    float ss=S[t]+S[t+64]+S[t+128]+S[t+192];
    float mm=fmaxf(fmaxf(M[t],M[t+64]),fmaxf(M[t+128],M[t+192]));
    int cnt=n1-n0;
    V[t]=ss/fmaxf((float)cnt,1.f);
    V[64+t]=(cnt>0)?mm:0.f;
  }
  __syncthreads();
  if(t<64){
    float acc=pb[t];
    for(int k=0;k<128;++k) acc+=V[k]*pW[k*64+t];
    out[(long)g*64+t]=acc;
  }
}

// ---------- host ----------
extern "C" void kernel_launch(void* const* d_in, const int* in_sizes, int n_in,
                              void* d_out, int out_size, void* d_ws, size_t ws_size,
                              hipStream_t stream){
  const int   NN[6]={100000,150000,500000,20000,5000,50000};
  const long  XO[6]={0,100000,250000,750000,770000,775000};
  const int   RS[12]={0,1,2,2,2,2,1,2,3,4,5,2};
  const int   RD[12]={1,2,3,4,5,2,0,1,2,2,2,2};
  const int   EC[12]={150000,500000,500000,500000,500000,500000,150000,500000,500000,500000,500000,500000};

  const float* xin[6];  for(int t=0;t<6;++t) xin[t]=(const float*)d_in[t];
  const float* embW[6]; const float* embB[6];
  for(int t=0;t<6;++t){ embW[t]=(const float*)d_in[6+2*t]; embB[t]=(const float*)d_in[7+2*t]; }
  const float* gatW =(const float*)d_in[18];
  const float* gatAs=(const float*)d_in[19];
  const float* gatAd=(const float*)d_in[20];
  const float* gatB =(const float*)d_in[21];
  const float* poolW=(const float*)d_in[22];
  const float* poolB=(const float*)d_in[23];
  const float* W1=(const float*)d_in[24];
  const float* b1=(const float*)d_in[25];
  const float* W2=(const float*)d_in[26];
  const float* b2=(const float*)d_in[27];
  const int* esrc[12]; const int* edst[12];
  for(int r=0;r<12;++r){ esrc[r]=(const int*)d_in[28+2*r]; edst[r]=(const int*)d_in[29+2*r]; }
  const int* batch=(const int*)d_in[52];
  float* out=(float*)d_out;
  (void)in_sizes; (void)n_in;

  EdgeTab et;
  GTab tab;
  int rpo=0, seo=0, asz=0, dsz=0;
  for(int r=0;r<12;++r){
    et.dst[r]=edst[r]; et.src[r]=esrc[r];
    et.seo[r]=seo; et.rpo[r]=rpo;
    et.nd[r]=NN[RD[r]]; et.ns[r]=NN[RS[r]];
    tab.rst[r]=RS[r]; tab.rdt[r]=RD[r];
    tab.seo[r]=seo; tab.rpo[r]=rpo;
    tab.aso[r]=asz; tab.ado[r]=dsz;
    seo+=EC[r]; rpo+=NN[RD[r]]+1;
    asz+=NN[RS[r]]; dsz+=NN[RD[r]];
  }
  et.seo[12]=seo; et.rpo[12]=rpo;
  const int Etot=seo;
  const int RPtot=rpo;
  tab.dszb=asz;
  for(int t=0;t<6;++t){ tab.nn[t]=NN[t]; tab.xo[t]=(int)XO[t]; }
  const int TORD[6]={4,3,5,2,1,0};
  int bo=0, abo=0;
  for(int i=0;i<6;++i){
    int t=TORD[i];
    tab.tord[i]=t;
    tab.bofs[i]=bo;   bo+=CDIV(NN[t],64);
    tab.abofs[i]=abo; abo+=CDIV(NN[t],256);
  }
  tab.bofs[6]=bo; tab.abofs[6]=abo;
  for(int t=0;t<6;++t){ tab.nrel[t]=0; tab.nrole[t]=0; }
  for(int r=0;r<12;++r){
    int dt=RD[r];
    tab.rel[dt][tab.nrel[dt]++]=r;
    int st=RS[r];
    tab.rwv[st][tab.nrole[st]]=r*2+0;   tab.rofs[st][tab.nrole[st]++]=tab.aso[r];
    tab.rwv[dt][tab.nrole[dt]]=r*2+1;   tab.rofs[dt][tab.nrole[dt]++]=asz+tab.ado[r];
  }

  // ---- workspace ----
  char* w=(char*)d_ws;
  size_t off=0;
  auto take=[&](size_t bytes)->void*{
    void* p=w+off; off+=(bytes+(size_t)255)&~(size_t)255; return p;
  };
  u16*   X1   =(u16*)  take(105600000);
  u16*   X2   =(u16*)  take(105600000);
  int*   RP   =(int*)  take((size_t)RPtot*4);
  int*   SRCS =(int*)  take((size_t)Etot*4);
  int*   BS   =(int*)  take(4096);
  f16*   AA   =(f16*)  take((size_t)(asz+dsz)*2);
  float* WV   =(float*)take(72*64*4);
  float* BSUM =(float*)take(4608);
  int*   GRP  =(int*)  take(4104);
  u16*   WT   =(u16*)  take(294912);
  u32*   MG   =(u32*)  take(288);
  size_t need=off;

  const int B=256;

  if(ws_size<need){
    kdiag<<<CDIV(out_size,B),B,0,stream>>>(out,out_size,(float)(ws_size>>20));
    return;
  }

  // weight prep (kwv also zeroes MG)
  kwconv<<<CDIV(147456,B),B,0,stream>>>(gatW,WT,147456);
  kwv<<<72,64,0,stream>>>(gatW,gatAs,gatAd,WV,MG);
  kbsum<<<18,64,0,stream>>>(gatB,BSUM);

  // CSR build: single-pass hist + scan + single-pass scatter
  int nbs=CDIV(RPtot,4096);
  kzeroi<<<CDIV(RPtot,B),B,0,stream>>>(RP,RPtot);
  khistAll<<<CDIV(Etot,B),B,0,stream>>>(et,RP,Etot);
  kscan1<<<nbs,256,0,stream>>>(RP,RP,BS,RPtot);
  kscan2b<<<1,256,0,stream>>>(BS,nbs);
  kscan3<<<CDIV(RPtot,B),B,0,stream>>>(RP,BS,RPtot);
  kscatterAll<<<CDIV(Etot,B),B,0,stream>>>(et,RP,SRCS,Etot);

  // embeddings (+ layer-0 alphas) -> X1
  kemb< 8><<<CDIV(NN[0],B),B,0,stream>>>(xin[0],embW[0],embB[0],X1+XO[0]*64,NN[0],WV,AA,tab,0);
  kemb< 6><<<CDIV(NN[1],B),B,0,stream>>>(xin[1],embW[1],embB[1],X1+XO[1]*64,NN[1],WV,AA,tab,1);
  kemb<12><<<CDIV(NN[2],B),B,0,stream>>>(xin[2],embW[2],embB[2],X1+XO[2]*64,NN[2],WV,AA,tab,2);
  kemb< 6><<<CDIV(NN[3],B),B,0,stream>>>(xin[3],embW[3],embB[3],X1+XO[3]*64,NN[3],WV,AA,tab,3);
  kemb< 5><<<CDIV(NN[4],B),B,0,stream>>>(xin[4],embW[4],embB[4],X1+XO[4]*64,NN[4],WV,AA,tab,4);
  kemb< 5><<<CDIV(NN[5],B),B,0,stream>>>(xin[5],embW[5],embB[5],X1+XO[5]*64,NN[5],WV,AA,tab,5);

  u16* Xc=X1; u16* Xn=X2;
  for(int l=0;l<3;++l){
    if(l>0) kalphaM<<<abo,256,0,stream>>>(Xc,WV+(size_t)l*1536,AA,tab);
    kmg<<<24*8,256,0,stream>>>(AA,MG+(size_t)l*24,tab);
    kfusedM2<<<bo,256,0,stream>>>(Xc,Xn,WT+(size_t)l*49152,AA,RP,SRCS,
                                  BSUM+(size_t)l*384,MG+(size_t)l*24,tab);
    u16* tmp=Xc; Xc=Xn; Xn=tmp;
  }

  kcls<<<CDIV(NN[2],B),B,0,stream>>>(Xc+XO[2]*64,W1,b1,W2,b2,out,NN[2]);

  kgrp<<<CDIV(1025,B),B,0,stream>>>(batch,GRP,NN[2]);
  kpoolf<<<1024,256,0,stream>>>(Xc+XO[2]*64,GRP,poolW,poolB,out+500000);
}